// Round 9
// baseline (89.957 us; speedup 1.0000x reference)
//
#include <hip/hip_runtime.h>
#include <math.h>

#define NTOK 4096
#define NDIM 1024
#define KTOT 2048
#define NEXP 64
#define NKC  8           // split-K factor
#define KCH  (KTOT / NKC)  // 256 k per wave-chunk
#define NSTEP (KCH / 32)   // 8 mfma K-steps per chunk

typedef _Float16 half8 __attribute__((ext_vector_type(8)));
typedef float    floatx4 __attribute__((ext_vector_type(4)));

#define XSCALE 16.0f
#define WSCALE 1024.0f
#define INVSCALE (1.0f / (16.0f * 1024.0f))

struct h2pair { _Float16 h, l; };
__device__ __forceinline__ h2pair split2(float v) {
    h2pair r;
    r.h = (_Float16)v;
    r.l = (_Float16)(v - (float)r.h);
    return r;
}

// ---------------------------------------------------------------------------
// prep_w: W (fp32) -> scaled fp16 hi/lo planes in FRAGMENT-MAJOR layout
//   WhT[((k>>3)*NEXP + e)*8 + (k&7)]
// so a B-fragment load (16 experts x one k-octet) is 256 B contiguous.
// Also computes ||w_e||^2.  grid = 64 blocks x 256 threads.
// ---------------------------------------------------------------------------
__global__ __launch_bounds__(256) void prep_w(const float* __restrict__ W,
                                              _Float16* __restrict__ WhT,
                                              _Float16* __restrict__ WlT,
                                              float* __restrict__ nrm) {
    const int e = blockIdx.x, t = threadIdx.x;   // t = k-octet 0..255
    const float* row = W + (size_t)e * KTOT + t * 8;
    const float4 a = *reinterpret_cast<const float4*>(row);
    const float4 b = *reinterpret_cast<const float4*>(row + 4);
    float ss = fmaf(a.x, a.x, fmaf(a.y, a.y, fmaf(a.z, a.z, fmaf(a.w, a.w, 0.f))));
    ss = fmaf(b.x, b.x, fmaf(b.y, b.y, fmaf(b.z, b.z, fmaf(b.w, b.w, ss))));

    const h2pair p0 = split2(a.x * WSCALE), p1 = split2(a.y * WSCALE);
    const h2pair p2 = split2(a.z * WSCALE), p3 = split2(a.w * WSCALE);
    const h2pair p4 = split2(b.x * WSCALE), p5 = split2(b.y * WSCALE);
    const h2pair p6 = split2(b.z * WSCALE), p7 = split2(b.w * WSCALE);
    half8 h, l;
    h[0]=p0.h; h[1]=p1.h; h[2]=p2.h; h[3]=p3.h; h[4]=p4.h; h[5]=p5.h; h[6]=p6.h; h[7]=p7.h;
    l[0]=p0.l; l[1]=p1.l; l[2]=p2.l; l[3]=p3.l; l[4]=p4.l; l[5]=p5.l; l[6]=p6.l; l[7]=p7.l;
    const size_t idx = ((size_t)t * NEXP + e) * 8;
    *reinterpret_cast<half8*>(WhT + idx) = h;
    *reinterpret_cast<half8*>(WlT + idx) = l;

    #pragma unroll
    for (int off = 32; off > 0; off >>= 1) ss += __shfl_down(ss, off, 64);
    __shared__ float red[4];
    const int lane = t & 63, wv = t >> 6;
    if (lane == 0) red[wv] = ss;
    __syncthreads();
    if (t == 0) nrm[e] = (red[0] + red[1]) + (red[2] + red[3]);
}

// ---------------------------------------------------------------------------
// gemm_frag: barrier-free, LDS-free split-K MFMA GEMM.
// Wave = 16 tokens x 64 experts x 256-k chunk.  A-fragment loaded per-lane
// straight from fp32 X (split to fp16 hi/lo in regs); B-fragments from the
// fragment-major fp16 planes (contiguous 256 B per load, L1/L2-hot).
// 3-pass mfma: xh*wh + xl*wh + xh*wl.  Norm partials folded in.
// grid = 512 blocks x 256 threads (2048 waves = NTOK/16 * NKC).
// ---------------------------------------------------------------------------
__global__ __launch_bounds__(256) void gemm_frag(const float* __restrict__ t1,
                                                 const float* __restrict__ t2,
                                                 const _Float16* __restrict__ WhT,
                                                 const _Float16* __restrict__ WlT,
                                                 float* __restrict__ Gp,
                                                 float* __restrict__ Cp) {
    const int tid  = threadIdx.x;
    const int lane = tid & 63;
    const int gw   = blockIdx.x * 4 + (tid >> 6);   // global wave 0..2047
    const int tokg = gw >> 3;                       // token group 0..255
    const int kc   = gw & 7;                        // split-K chunk
    const int tok0 = tokg * 16;
    const int kbase = kc * KCH;
    const int n  = lane & 15;                       // fragment row (token / expert)
    const int fq = lane >> 4;                       // k-octet selector

    // X: lane reads token tok0+n, k = kbase + step*32 + fq*8 .. +7
    const float* __restrict__ xb = ((kbase < NDIM)
        ? (t1 + (size_t)(tok0 + n) * NDIM + kbase)
        : (t2 + (size_t)(tok0 + n) * NDIM + (kbase - NDIM))) + fq * 8;
    // W: fragment-major; k-octet index = kbase/8 + step*4 + fq, expert row 16j+n
    const _Float16* __restrict__ whb = WhT + ((size_t)(kbase >> 3) + fq) * (NEXP * 8) + n * 8;
    const _Float16* __restrict__ wlb = WlT + ((size_t)(kbase >> 3) + fq) * (NEXP * 8) + n * 8;

    floatx4 acc[4];
    #pragma unroll
    for (int j = 0; j < 4; ++j) { acc[j][0]=0.f; acc[j][1]=0.f; acc[j][2]=0.f; acc[j][3]=0.f; }
    float ssx = 0.f;

    #pragma unroll
    for (int s = 0; s < NSTEP; ++s) {
        const float4 x0 = *reinterpret_cast<const float4*>(xb + s * 32);
        const float4 x1 = *reinterpret_cast<const float4*>(xb + s * 32 + 4);
        half8 bh[4], bl[4];
        #pragma unroll
        for (int j = 0; j < 4; ++j) {
            bh[j] = *reinterpret_cast<const half8*>(whb + (size_t)s * 4 * (NEXP * 8) + j * 128);
            bl[j] = *reinterpret_cast<const half8*>(wlb + (size_t)s * 4 * (NEXP * 8) + j * 128);
        }
        ssx = fmaf(x0.x, x0.x, fmaf(x0.y, x0.y, fmaf(x0.z, x0.z, fmaf(x0.w, x0.w, ssx))));
        ssx = fmaf(x1.x, x1.x, fmaf(x1.y, x1.y, fmaf(x1.z, x1.z, fmaf(x1.w, x1.w, ssx))));
        const h2pair q0 = split2(x0.x * XSCALE), q1 = split2(x0.y * XSCALE);
        const h2pair q2 = split2(x0.z * XSCALE), q3 = split2(x0.w * XSCALE);
        const h2pair q4 = split2(x1.x * XSCALE), q5 = split2(x1.y * XSCALE);
        const h2pair q6 = split2(x1.z * XSCALE), q7 = split2(x1.w * XSCALE);
        half8 ah, al;
        ah[0]=q0.h; ah[1]=q1.h; ah[2]=q2.h; ah[3]=q3.h; ah[4]=q4.h; ah[5]=q5.h; ah[6]=q6.h; ah[7]=q7.h;
        al[0]=q0.l; al[1]=q1.l; al[2]=q2.l; al[3]=q3.l; al[4]=q4.l; al[5]=q5.l; al[6]=q6.l; al[7]=q7.l;
        #pragma unroll
        for (int j = 0; j < 4; ++j)
            acc[j] = __builtin_amdgcn_mfma_f32_16x16x32_f16(ah, bh[j], acc[j], 0, 0, 0);
        #pragma unroll
        for (int j = 0; j < 4; ++j)
            acc[j] = __builtin_amdgcn_mfma_f32_16x16x32_f16(al, bh[j], acc[j], 0, 0, 0);
        #pragma unroll
        for (int j = 0; j < 4; ++j)
            acc[j] = __builtin_amdgcn_mfma_f32_16x16x32_f16(ah, bl[j], acc[j], 0, 0, 0);
    }

    // ---- dot partials (C/D layout: col(n)=lane&15, row(m)=fq*4+reg) ----
    #pragma unroll
    for (int j = 0; j < 4; ++j) {
        #pragma unroll
        for (int i = 0; i < 4; ++i) {
            Gp[((size_t)kc * NTOK + tok0 + fq * 4 + i) * NEXP + 16 * j + n] = acc[j][i];
        }
    }

    // ---- token norm partials: combine the 4 fq-lanes of each token ----
    ssx += __shfl_xor(ssx, 16, 64);
    ssx += __shfl_xor(ssx, 32, 64);
    if (lane < 16)
        Cp[(size_t)kc * NTOK + tok0 + lane] = ssx;
}

// ---------------------------------------------------------------------------
// Finalize: one wave per token, lane = expert.  Compile-time NKC unroll so
// all partial loads issue back-to-back (one memory latency).
// ---------------------------------------------------------------------------
__global__ __launch_bounds__(256) void finalize(const float* __restrict__ Gp,
                                                const float* __restrict__ Cp,
                                                const float* __restrict__ nrm,
                                                float* __restrict__ out) {
    const int wv = threadIdx.x >> 6, lane = threadIdx.x & 63;
    const int token = blockIdx.x * 4 + wv;

    float gsum = 0.f, csum = 0.f;
    #pragma unroll
    for (int cix = 0; cix < NKC; ++cix) {
        gsum += Gp[((size_t)cix * NTOK + token) * NEXP + lane];
        csum += Cp[(size_t)cix * NTOK + token];
    }
    const float nv = nrm[lane];

    const float S = fmaf(-2.f * INVSCALE, gsum, csum) + nv;
    const float logit = -sqrtf(S);

    float v1 = logit; int i1 = lane;
    #pragma unroll
    for (int off = 32; off > 0; off >>= 1) {
        float ov = __shfl_xor(v1, off, 64);
        int   oi = __shfl_xor(i1, off, 64);
        if (ov > v1 || (ov == v1 && oi < i1)) { v1 = ov; i1 = oi; }
    }
    float v2 = (lane == i1) ? -__builtin_inff() : logit;
    int   i2 = lane;
    #pragma unroll
    for (int off = 32; off > 0; off >>= 1) {
        float ov = __shfl_xor(v2, off, 64);
        int   oi = __shfl_xor(i2, off, 64);
        if (ov > v2 || (ov == v2 && oi < i2)) { v2 = ov; i2 = oi; }
    }
    const float e2  = expf(v2 - v1);
    const float inv = 1.f / (1.f + e2);
    const float o = (lane == i1) ? inv : ((lane == i2) ? e2 * inv : 0.f);
    out[(size_t)token * NEXP + lane] = o;
}

// ---------------------------------------------------------------------------
extern "C" void kernel_launch(void* const* d_in, const int* in_sizes, int n_in,
                              void* d_out, int out_size, void* d_ws, size_t ws_size,
                              hipStream_t stream) {
    const float* t1 = (const float*)d_in[0];
    const float* t2 = (const float*)d_in[1];
    const float* W  = (const float*)d_in[2];
    float* out = (float*)d_out;

    char* ws = (char*)d_ws;
    float*    Gp  = (float*)ws;                               // NKC*NTOK*NEXP f (8 MB)
    float*    Cp  = Gp + (size_t)NKC * NTOK * NEXP;           // NKC*NTOK f
    float*    nrm = Cp + (size_t)NKC * NTOK;                  // NEXP f
    _Float16* WhT = (_Float16*)(nrm + NEXP);                  // NEXP*KTOT halves
    _Float16* WlT = WhT + (size_t)NEXP * KTOT;                // NEXP*KTOT halves

    prep_w<<<NEXP, 256, 0, stream>>>(W, WhT, WlT, nrm);
    gemm_frag<<<(NTOK / 16) * NKC / 4, 256, 0, stream>>>(t1, t2, WhT, WlT, Gp, Cp);
    finalize<<<NTOK / 4, 256, 0, stream>>>(Gp, Cp, nrm, out);
}

// Round 10
// 83.824 us; speedup vs baseline: 1.0732x; 1.0732x over previous
//
#include <hip/hip_runtime.h>
#include <math.h>

#define NTOK 4096
#define NDIM 1024
#define KTOT 2048
#define NEXP 64
#define NWAVE 8            // intra-block split-K waves
#define KCH  (KTOT / NWAVE)  // 256 k per wave
#define NSTEP (KCH / 32)     // 8 mfma K-steps per wave
#define RS   68              // LDS row stride (floats) for the reduce buffer

typedef _Float16 half8 __attribute__((ext_vector_type(8)));
typedef float    floatx4 __attribute__((ext_vector_type(4)));

#define XSCALE 16.0f
#define WSCALE 1024.0f
#define INVSCALE (1.0f / (16.0f * 1024.0f))

struct h2pair { _Float16 h, l; };
__device__ __forceinline__ h2pair split2(float v) {
    h2pair r;
    r.h = (_Float16)v;
    r.l = (_Float16)(v - (float)r.h);
    return r;
}

// ---------------------------------------------------------------------------
// prep_w: W (fp32) -> scaled fp16 hi/lo planes in FRAGMENT-MAJOR layout
//   WhT[((k>>3)*NEXP + e)*8 + (k&7)]
// so a B-fragment load (16 experts x one k-octet) is 256 B contiguous.
// Also computes ||w_e||^2.  grid = 64 blocks x 256 threads.
// ---------------------------------------------------------------------------
__global__ __launch_bounds__(256) void prep_w(const float* __restrict__ W,
                                              _Float16* __restrict__ WhT,
                                              _Float16* __restrict__ WlT,
                                              float* __restrict__ nrm) {
    const int e = blockIdx.x, t = threadIdx.x;   // t = k-octet 0..255
    const float* row = W + (size_t)e * KTOT + t * 8;
    const float4 a = *reinterpret_cast<const float4*>(row);
    const float4 b = *reinterpret_cast<const float4*>(row + 4);
    float ss = fmaf(a.x, a.x, fmaf(a.y, a.y, fmaf(a.z, a.z, fmaf(a.w, a.w, 0.f))));
    ss = fmaf(b.x, b.x, fmaf(b.y, b.y, fmaf(b.z, b.z, fmaf(b.w, b.w, ss))));

    const h2pair p0 = split2(a.x * WSCALE), p1 = split2(a.y * WSCALE);
    const h2pair p2 = split2(a.z * WSCALE), p3 = split2(a.w * WSCALE);
    const h2pair p4 = split2(b.x * WSCALE), p5 = split2(b.y * WSCALE);
    const h2pair p6 = split2(b.z * WSCALE), p7 = split2(b.w * WSCALE);
    half8 h, l;
    h[0]=p0.h; h[1]=p1.h; h[2]=p2.h; h[3]=p3.h; h[4]=p4.h; h[5]=p5.h; h[6]=p6.h; h[7]=p7.h;
    l[0]=p0.l; l[1]=p1.l; l[2]=p2.l; l[3]=p3.l; l[4]=p4.l; l[5]=p5.l; l[6]=p6.l; l[7]=p7.l;
    const size_t idx = ((size_t)t * NEXP + e) * 8;
    *reinterpret_cast<half8*>(WhT + idx) = h;
    *reinterpret_cast<half8*>(WlT + idx) = l;

    #pragma unroll
    for (int off = 32; off > 0; off >>= 1) ss += __shfl_down(ss, off, 64);
    __shared__ float red[4];
    const int lane = t & 63, wv = t >> 6;
    if (lane == 0) red[wv] = ss;
    __syncthreads();
    if (t == 0) nrm[e] = (red[0] + red[1]) + (red[2] + red[3]);
}

// ---------------------------------------------------------------------------
// gate_fused: barrier-free MFMA main loop (R9 structure) + intra-block
// split-K LDS reduction + top-2 softmax epilogue, all in one kernel.
// Block = 512 threads = 8 waves; wave w handles k-chunk [w*256,(w+1)*256)
// for the block's 16 tokens.  grid = NTOK/16 = 256 blocks.
// Cross-wave sum order w=0..7 is fixed -> deterministic, and matches the
// previous finalize kernel's c=0..7 order -> bit-identical output.
// ---------------------------------------------------------------------------
__global__ __launch_bounds__(512) void gate_fused(const float* __restrict__ t1,
                                                  const float* __restrict__ t2,
                                                  const _Float16* __restrict__ WhT,
                                                  const _Float16* __restrict__ WlT,
                                                  const float* __restrict__ nrm,
                                                  float* __restrict__ out) {
    __shared__ float Sd[NWAVE][16 * RS];   // per-wave 16x64 partial dots (stride 68)
    __shared__ float Cn[NWAVE][16];        // per-wave per-token ||x||^2 partials

    const int tid  = threadIdx.x;
    const int lane = tid & 63;
    const int wv   = tid >> 6;            // 0..7 = split-K chunk
    const int tok0 = blockIdx.x * 16;
    const int kbase = wv * KCH;
    const int n  = lane & 15;             // fragment row (token / expert)
    const int fq = lane >> 4;             // k-octet selector

    // X: lane reads token tok0+n, k = kbase + step*32 + fq*8 .. +7
    const float* __restrict__ xb = ((kbase < NDIM)
        ? (t1 + (size_t)(tok0 + n) * NDIM + kbase)
        : (t2 + (size_t)(tok0 + n) * NDIM + (kbase - NDIM))) + fq * 8;
    // W: fragment-major; k-octet index = kbase/8 + step*4 + fq, expert row 16j+n
    const _Float16* __restrict__ whb = WhT + ((size_t)(kbase >> 3) + fq) * (NEXP * 8) + n * 8;
    const _Float16* __restrict__ wlb = WlT + ((size_t)(kbase >> 3) + fq) * (NEXP * 8) + n * 8;

    floatx4 acc[4];
    #pragma unroll
    for (int j = 0; j < 4; ++j) { acc[j][0]=0.f; acc[j][1]=0.f; acc[j][2]=0.f; acc[j][3]=0.f; }
    float ssx = 0.f;

    #pragma unroll
    for (int s = 0; s < NSTEP; ++s) {
        const float4 x0 = *reinterpret_cast<const float4*>(xb + s * 32);
        const float4 x1 = *reinterpret_cast<const float4*>(xb + s * 32 + 4);
        half8 bh[4], bl[4];
        #pragma unroll
        for (int j = 0; j < 4; ++j) {
            bh[j] = *reinterpret_cast<const half8*>(whb + (size_t)s * 4 * (NEXP * 8) + j * 128);
            bl[j] = *reinterpret_cast<const half8*>(wlb + (size_t)s * 4 * (NEXP * 8) + j * 128);
        }
        ssx = fmaf(x0.x, x0.x, fmaf(x0.y, x0.y, fmaf(x0.z, x0.z, fmaf(x0.w, x0.w, ssx))));
        ssx = fmaf(x1.x, x1.x, fmaf(x1.y, x1.y, fmaf(x1.z, x1.z, fmaf(x1.w, x1.w, ssx))));
        const h2pair q0 = split2(x0.x * XSCALE), q1 = split2(x0.y * XSCALE);
        const h2pair q2 = split2(x0.z * XSCALE), q3 = split2(x0.w * XSCALE);
        const h2pair q4 = split2(x1.x * XSCALE), q5 = split2(x1.y * XSCALE);
        const h2pair q6 = split2(x1.z * XSCALE), q7 = split2(x1.w * XSCALE);
        half8 ah, al;
        ah[0]=q0.h; ah[1]=q1.h; ah[2]=q2.h; ah[3]=q3.h; ah[4]=q4.h; ah[5]=q5.h; ah[6]=q6.h; ah[7]=q7.h;
        al[0]=q0.l; al[1]=q1.l; al[2]=q2.l; al[3]=q3.l; al[4]=q4.l; al[5]=q5.l; al[6]=q6.l; al[7]=q7.l;
        #pragma unroll
        for (int j = 0; j < 4; ++j)
            acc[j] = __builtin_amdgcn_mfma_f32_16x16x32_f16(ah, bh[j], acc[j], 0, 0, 0);
        #pragma unroll
        for (int j = 0; j < 4; ++j)
            acc[j] = __builtin_amdgcn_mfma_f32_16x16x32_f16(al, bh[j], acc[j], 0, 0, 0);
        #pragma unroll
        for (int j = 0; j < 4; ++j)
            acc[j] = __builtin_amdgcn_mfma_f32_16x16x32_f16(ah, bl[j], acc[j], 0, 0, 0);
    }

    // ---- deposit partial dots in LDS (C/D layout: token=fq*4+i, expert=16j+n)
    #pragma unroll
    for (int j = 0; j < 4; ++j) {
        #pragma unroll
        for (int i = 0; i < 4; ++i)
            Sd[wv][(fq * 4 + i) * RS + 16 * j + n] = acc[j][i];
    }
    // ---- token norm partials: combine the 4 fq-lanes of each token ----
    ssx += __shfl_xor(ssx, 16, 64);
    ssx += __shfl_xor(ssx, 32, 64);
    if (lane < 16) Cn[wv][lane] = ssx;
    __syncthreads();

    // ---- epilogue: wave w finalizes tokens 2w, 2w+1 (lane = expert) ----
    #pragma unroll
    for (int tt = 0; tt < 2; ++tt) {
        const int t = wv * 2 + tt;
        float gsum = 0.f, csum = 0.f;
        #pragma unroll
        for (int w = 0; w < NWAVE; ++w) {
            gsum += Sd[w][t * RS + lane];
            csum += Cn[w][t];
        }
        const float S = fmaf(-2.f * INVSCALE, gsum, csum) + nrm[lane];
        const float logit = -sqrtf(S);

        float v1 = logit; int i1 = lane;
        #pragma unroll
        for (int off = 32; off > 0; off >>= 1) {
            float ov = __shfl_xor(v1, off, 64);
            int   oi = __shfl_xor(i1, off, 64);
            if (ov > v1 || (ov == v1 && oi < i1)) { v1 = ov; i1 = oi; }
        }
        float v2 = (lane == i1) ? -__builtin_inff() : logit;
        int   i2 = lane;
        #pragma unroll
        for (int off = 32; off > 0; off >>= 1) {
            float ov = __shfl_xor(v2, off, 64);
            int   oi = __shfl_xor(i2, off, 64);
            if (ov > v2 || (ov == v2 && oi < i2)) { v2 = ov; i2 = oi; }
        }
        const float e2  = expf(v2 - v1);
        const float inv = 1.f / (1.f + e2);
        const float o = (lane == i1) ? inv : ((lane == i2) ? e2 * inv : 0.f);
        out[(size_t)(tok0 + t) * NEXP + lane] = o;
    }
}

// ---------------------------------------------------------------------------
extern "C" void kernel_launch(void* const* d_in, const int* in_sizes, int n_in,
                              void* d_out, int out_size, void* d_ws, size_t ws_size,
                              hipStream_t stream) {
    const float* t1 = (const float*)d_in[0];
    const float* t2 = (const float*)d_in[1];
    const float* W  = (const float*)d_in[2];
    float* out = (float*)d_out;

    char* ws = (char*)d_ws;
    float*    nrm = (float*)ws;                    // NEXP floats
    _Float16* WhT = (_Float16*)(nrm + NEXP);       // NEXP*KTOT halves (256 KB)
    _Float16* WlT = WhT + (size_t)NEXP * KTOT;     // NEXP*KTOT halves

    prep_w<<<NEXP, 256, 0, stream>>>(W, WhT, WlT, nrm);
    gate_fused<<<NTOK / 16, 512, 0, stream>>>(t1, t2, WhT, WlT, nrm, out);
}